// Round 8
// baseline (896.236 us; speedup 1.0000x reference)
//
#include <hip/hip_runtime.h>
#include <math.h>

#define NN 50000
#define NE 800000
#define NG 128
#define DIM 128
#define CLASSES 10

// ---------------- utility ----------------

__global__ void zero_kernel(float* __restrict__ p, int n4) {
    int i = blockIdx.x * blockDim.x + threadIdx.x;
    int stride = gridDim.x * blockDim.x;
    float4 z = make_float4(0.f, 0.f, 0.f, 0.f);
    for (; i < n4; i += stride) ((float4*)p)[i] = z;
}

__global__ void zero_int_kernel(int* __restrict__ p, int n) {
    int i = blockIdx.x * blockDim.x + threadIdx.x;
    int stride = gridDim.x * blockDim.x;
    for (; i < n; i += stride) p[i] = 0;
}

// ---------------- CSR build ----------------

__global__ void count_kernel(const int* __restrict__ dst, int* __restrict__ cnt, int E) {
    int i = blockIdx.x * blockDim.x + threadIdx.x;
    int stride = gridDim.x * blockDim.x;
    for (; i < E; i += stride) atomicAdd(&cnt[dst[i]], 1);
}

__global__ void norm_from_cnt_kernel(const int* __restrict__ cnt, float* __restrict__ nrm, int n) {
    int i = blockIdx.x * blockDim.x + threadIdx.x;
    if (i < n) {
        float v = (float)cnt[i];
        v = v < 1.f ? 1.f : v;
        nrm[i] = 1.0f / sqrtf(v);
    }
}

// single-block exclusive scan via wave shuffles
__global__ __launch_bounds__(1024) void scan_kernel(const int* __restrict__ cnt,
                                                    int* __restrict__ rowptr, int n) {
    __shared__ int wsum[16];
    __shared__ int base;
    int t = threadIdx.x;
    int lane = t & 63, wv = t >> 6;
    if (t == 0) { base = 0; rowptr[0] = 0; }
    __syncthreads();
    for (int start = 0; start < n; start += 1024) {
        int i = start + t;
        int v = (i < n) ? cnt[i] : 0;
#pragma unroll
        for (int off = 1; off < 64; off <<= 1) {
            int u = __shfl_up(v, off);
            if (lane >= off) v += u;
        }
        if (lane == 63) wsum[wv] = v;
        __syncthreads();
        if (wv == 0) {
            int s = (lane < 16) ? wsum[lane] : 0;
#pragma unroll
            for (int off = 1; off < 16; off <<= 1) {
                int u = __shfl_up(s, off);
                if (lane >= off) s += u;
            }
            if (lane < 16) wsum[lane] = s;
        }
        __syncthreads();
        int woff = (wv > 0) ? wsum[wv - 1] : 0;
        if (i < n) rowptr[i + 1] = base + woff + v;
        __syncthreads();
        if (t == 0) base += wsum[15];
        __syncthreads();
    }
}

__global__ void copy_int_kernel(const int* __restrict__ a, int* __restrict__ b, int n) {
    int i = blockIdx.x * blockDim.x + threadIdx.x;
    int stride = gridDim.x * blockDim.x;
    for (; i < n; i += stride) b[i] = a[i];
}

__global__ void fill_kernel(const int* __restrict__ src, const int* __restrict__ dst,
                            int* __restrict__ rowcur, int* __restrict__ esrc, int E) {
    int i = blockIdx.x * blockDim.x + threadIdx.x;
    int stride = gridDim.x * blockDim.x;
    for (; i < E; i += stride) {
        int pos = atomicAdd(&rowcur[dst[i]], 1);
        esrc[pos] = src[i];
    }
}

// ---------------- propagation hop ----------------
// out[i] = nrm[i] * sum_{e: dst=i} feat[src]*nrm[src]
// Memory-hierarchy-bound at ~4.7 TB/s effective gather (R2/R3/R4 all ~87us);
// structure kept stable.

__global__ __launch_bounds__(256) void gather_hop_kernel(
    const float* __restrict__ feat, const float* __restrict__ nrm,
    const int* __restrict__ rowptr, const int* __restrict__ esrc,
    float* __restrict__ out, int n) {
    int wid = (blockIdx.x * blockDim.x + threadIdx.x) >> 6;
    int lane = threadIdx.x & 63;
    if (wid >= n) return;
    int beg = rowptr[wid], end = rowptr[wid + 1];
    int deg = end - beg;
    int half = lane >> 5;   // which edge of the pair this half-wave handles
    int l32 = lane & 31;    // float4 slot within the 512B row
    float4 acc = make_float4(0.f, 0.f, 0.f, 0.f);
    for (int b = 0; b < deg; b += 64) {
        int rem = deg - b; if (rem > 64) rem = 64;
        int sE = 0; float wE = 0.f;   // lanes >= rem keep (0, 0) -> phantom edges are no-ops
        if (lane < rem) {
            sE = esrc[beg + b + lane];
            wE = nrm[sE];
        }
        int k = 0;
        for (; k + 7 < rem; k += 8) {
#pragma unroll
            for (int u = 0; u < 4; ++u) {
                int sel = k + 2 * u + half;
                int s = __shfl(sE, sel);
                float w = __shfl(wE, sel);
                float4 v = ((const float4*)(feat + (size_t)s * DIM))[l32];
                acc.x += v.x * w; acc.y += v.y * w;
                acc.z += v.z * w; acc.w += v.w * w;
            }
        }
        for (; k < rem; k += 2) {
            int sel = k + half;           // may point at a phantom edge: w=0 there
            int s = __shfl(sE, sel);
            float w = __shfl(wE, sel);
            float4 v = ((const float4*)(feat + (size_t)s * DIM))[l32];
            acc.x += v.x * w; acc.y += v.y * w;
            acc.z += v.z * w; acc.w += v.w * w;
        }
    }
    acc.x += __shfl_xor(acc.x, 32);
    acc.y += __shfl_xor(acc.y, 32);
    acc.z += __shfl_xor(acc.z, 32);
    acc.w += __shfl_xor(acc.w, 32);
    float nd = nrm[wid];
    if (lane < 32) {
        ((float4*)(out + (size_t)wid * DIM))[l32] =
            make_float4(acc.x * nd, acc.y * nd, acc.z * nd, acc.w * nd);
    }
}

// ---------------- fp32 GEMM: out[M,128] = relu([A0|A1|A2] @ W + b) ----------------
// BM=64 tile, 256 threads, per-thread 4x8. Grid = 782 blocks (~3/CU, 3 waves/SIMD)
// to fix the 13% occupancy / latency-bound profile of the BM=128 version.
// Per-thread cols split {c0..c0+3, c0+64..c0+67}: Wt reads are 16 contiguous
// 16B lines (2-way = free); As read is a 4-address broadcast (conflict-free).
// Register prefetch of next K-chunk overlaps global latency with FMA phase.
// In-place (out aliases A0) safe: each block reads only its own 64 rows.

#define BM 64
#define BK 32

__global__ __launch_bounds__(256) void gemm_kernel(
    const float* __restrict__ A0, const float* __restrict__ A1, const float* __restrict__ A2,
    const float* __restrict__ W, const float* __restrict__ bias,
    float* __restrict__ out, int M) {
    __shared__ float As[BK][BM + 4];   // transposed A tile
    __shared__ float Wt[BK][DIM];

    int tid = threadIdx.x;
    int row0 = blockIdx.x * BM;
    int r0 = (tid >> 4) * 4;   // row group: 16 groups x 4 rows = 64
    int c0 = (tid & 15) * 4;   // col group: {c0..c0+3} and {c0+64..c0+67}

    // staging coords
    int ar = tid >> 3;         // A row within tile (+32*it, it<2)
    int ak = (tid & 7) * 4;    // A k4
    int wk = tid >> 5;         // W k within chunk (+8*it, it<4)
    int wc = (tid & 31) * 4;   // W col

    const float* parts[3] = {A0, A1, A2};

    float4 pa[2], pw[4];
    // preload chunk 0 (p=0, kc=0)
#pragma unroll
    for (int it = 0; it < 2; ++it) {
        int grow = row0 + ar + 32 * it;
        pa[it] = (grow < M) ? *(const float4*)(A0 + (size_t)grow * DIM + ak)
                            : make_float4(0.f, 0.f, 0.f, 0.f);
    }
#pragma unroll
    for (int it = 0; it < 4; ++it) {
        pw[it] = *(const float4*)(W + (size_t)(wk + 8 * it) * DIM + wc);
    }

    float acc[4][8];
#pragma unroll
    for (int i = 0; i < 4; i++)
#pragma unroll
        for (int j = 0; j < 8; j++) acc[i][j] = 0.f;

    for (int t = 0; t < 12; ++t) {
        __syncthreads();
        // regs -> LDS
#pragma unroll
        for (int it = 0; it < 2; ++it) {
            int r = ar + 32 * it;
            As[ak + 0][r] = pa[it].x;
            As[ak + 1][r] = pa[it].y;
            As[ak + 2][r] = pa[it].z;
            As[ak + 3][r] = pa[it].w;
        }
#pragma unroll
        for (int it = 0; it < 4; ++it) {
            *(float4*)(&Wt[wk + 8 * it][wc]) = pw[it];
        }
        __syncthreads();
        // issue next chunk's loads; latency hides under the FMA block below
        if (t < 11) {
            int tn = t + 1;
            const float* A = parts[tn >> 2];
            int kc = (tn & 3) * BK;
#pragma unroll
            for (int it = 0; it < 2; ++it) {
                int grow = row0 + ar + 32 * it;
                pa[it] = (grow < M) ? *(const float4*)(A + (size_t)grow * DIM + kc + ak)
                                    : make_float4(0.f, 0.f, 0.f, 0.f);
            }
#pragma unroll
            for (int it = 0; it < 4; ++it) {
                pw[it] = *(const float4*)(W + (size_t)((tn >> 2) * DIM + kc + wk + 8 * it) * DIM + wc);
            }
        }
#pragma unroll
        for (int kk = 0; kk < BK; ++kk) {
            float4 a0 = *(const float4*)(&As[kk][r0]);
            float4 w0 = *(const float4*)(&Wt[kk][c0]);
            float4 w1 = *(const float4*)(&Wt[kk][c0 + 64]);
            float a[4] = {a0.x, a0.y, a0.z, a0.w};
            float w[8] = {w0.x, w0.y, w0.z, w0.w, w1.x, w1.y, w1.z, w1.w};
#pragma unroll
            for (int i = 0; i < 4; i++)
#pragma unroll
                for (int j = 0; j < 8; j++) acc[i][j] += a[i] * w[j];
        }
    }

    // epilogue: bias + relu + float4 stores
#pragma unroll
    for (int i = 0; i < 4; i++) {
        int grow = row0 + r0 + i;
        if (grow < M) {
            float4 o0, o1;
            o0.x = acc[i][0] + bias[c0 + 0]; o0.y = acc[i][1] + bias[c0 + 1];
            o0.z = acc[i][2] + bias[c0 + 2]; o0.w = acc[i][3] + bias[c0 + 3];
            o1.x = acc[i][4] + bias[c0 + 64 + 0]; o1.y = acc[i][5] + bias[c0 + 64 + 1];
            o1.z = acc[i][6] + bias[c0 + 64 + 2]; o1.w = acc[i][7] + bias[c0 + 64 + 3];
            o0.x = o0.x > 0.f ? o0.x : 0.f; o0.y = o0.y > 0.f ? o0.y : 0.f;
            o0.z = o0.z > 0.f ? o0.z : 0.f; o0.w = o0.w > 0.f ? o0.w : 0.f;
            o1.x = o1.x > 0.f ? o1.x : 0.f; o1.y = o1.y > 0.f ? o1.y : 0.f;
            o1.z = o1.z > 0.f ? o1.z : 0.f; o1.w = o1.w > 0.f ? o1.w : 0.f;
            *(float4*)(out + (size_t)grow * DIM + c0) = o0;
            *(float4*)(out + (size_t)grow * DIM + c0 + 64) = o1;
        }
    }
}

// ---------------- pooling + head ----------------

#define PCHUNK 64

__global__ __launch_bounds__(128) void pool_partial_kernel(
    const float* __restrict__ h, const int* __restrict__ gid,
    float* __restrict__ gsum, int n) {
    int d = threadIdx.x;
    int i0 = blockIdx.x * PCHUNK;
    if (i0 >= n) return;
    int i1 = i0 + PCHUNK; if (i1 > n) i1 = n;
    int curg = gid[i0];
    float acc = 0.f;
    for (int i = i0; i < i1; ++i) {
        int g = gid[i];
        if (g != curg) {
            atomicAdd(&gsum[(size_t)curg * DIM + d], acc);
            acc = 0.f;
            curg = g;
        }
        acc += h[(size_t)i * DIM + d];
    }
    atomicAdd(&gsum[(size_t)curg * DIM + d], acc);
}

__global__ __launch_bounds__(128) void head_kernel(
    const float* __restrict__ gsum, const int* __restrict__ gid,
    const float* __restrict__ Wc, const float* __restrict__ bc,
    float* __restrict__ out) {
    __shared__ float v[DIM];
    __shared__ int sbeg, send;
    int g = blockIdx.x;
    int t = threadIdx.x;
    if (t == 0) {
        int lo = 0, hi = NN;
        while (lo < hi) { int m = (lo + hi) >> 1; if (gid[m] < g) lo = m + 1; else hi = m; }
        sbeg = lo;
    }
    if (t == 1) {
        int lo = 0, hi = NN;
        while (lo < hi) { int m = (lo + hi) >> 1; if (gid[m] < g + 1) lo = m + 1; else hi = m; }
        send = lo;
    }
    __syncthreads();
    float c = (float)(send - sbeg);
    c = c < 1.f ? 1.f : c;
    v[t] = gsum[(size_t)g * DIM + t] / c;
    __syncthreads();
    if (t < CLASSES) {
        float o = bc[t];
#pragma unroll 16
        for (int d = 0; d < DIM; ++d) o += v[d] * Wc[d * CLASSES + t];
        out[g * CLASSES + t] = o;
    }
}

// ---------------- launch ----------------

extern "C" void kernel_launch(void* const* d_in, const int* in_sizes, int n_in,
                              void* d_out, int out_size, void* d_ws, size_t ws_size,
                              hipStream_t stream) {
    const float* x   = (const float*)d_in[0];
    const int*   src = (const int*)d_in[1];
    const int*   dst = (const int*)d_in[2];
    const int*   gid = (const int*)d_in[3];
    const float* W0  = (const float*)d_in[4];
    const float* b0  = (const float*)d_in[5];
    const float* W1  = (const float*)d_in[6];
    const float* b1  = (const float*)d_in[7];
    const float* W2  = (const float*)d_in[8];
    const float* b2  = (const float*)d_in[9];
    const float* Wc  = (const float*)d_in[10];
    const float* bc  = (const float*)d_in[11];
    float* out = (float*)d_out;

    // workspace: floats nrm[N] | h[N*D] | f1[N*D] | f2[N*D] | gsum[G*D]
    //            ints   cnt[N] | rowptr[N+1] | esrc[E]
    float* nrm  = (float*)d_ws;
    float* h    = nrm + NN;
    float* f1   = h + (size_t)NN * DIM;
    float* f2   = f1 + (size_t)NN * DIM;
    float* gsum = f2 + (size_t)NN * DIM;
    int* cnt    = (int*)(gsum + (size_t)NG * DIM);
    int* rowptr = cnt + NN;
    int* esrc   = rowptr + NN + 1;

    // CSR build (amortized over 6 hops)
    zero_int_kernel<<<64, 256, 0, stream>>>(cnt, NN);
    count_kernel<<<1024, 256, 0, stream>>>(dst, cnt, NE);
    norm_from_cnt_kernel<<<(NN + 255) / 256, 256, 0, stream>>>(cnt, nrm, NN);
    scan_kernel<<<1, 1024, 0, stream>>>(cnt, rowptr, NN);
    copy_int_kernel<<<64, 256, 0, stream>>>(rowptr, cnt, NN);  // cnt becomes rowcur
    fill_kernel<<<1024, 256, 0, stream>>>(src, dst, cnt, esrc, NE);

    const float* Ws_[3] = {W0, W1, W2};
    const float* bs_[3] = {b0, b1, b2};
    const float* featIn = x;
    const int hop_blocks = (NN * 64 + 255) / 256;
    for (int l = 0; l < 3; ++l) {
        gather_hop_kernel<<<hop_blocks, 256, 0, stream>>>(featIn, nrm, rowptr, esrc, f1, NN);
        gather_hop_kernel<<<hop_blocks, 256, 0, stream>>>(f1, nrm, rowptr, esrc, f2, NN);
        gemm_kernel<<<(NN + BM - 1) / BM, 256, 0, stream>>>(featIn, f1, f2, Ws_[l], bs_[l], h, NN);
        featIn = h;
    }

    // pooling + head
    zero_kernel<<<16, 256, 0, stream>>>(gsum, NG * DIM / 4);
    pool_partial_kernel<<<(NN + PCHUNK - 1) / PCHUNK, 128, 0, stream>>>(h, gid, gsum, NN);
    head_kernel<<<NG, DIM, 0, stream>>>(gsum, gid, Wc, bc, out);
}

// Round 13
// 843.518 us; speedup vs baseline: 1.0625x; 1.0625x over previous
//
#include <hip/hip_runtime.h>
#include <hip/hip_fp16.h>
#include <math.h>

#define NN 50000
#define NE 800000
#define NG 128
#define DIM 128
#define CLASSES 10

// ---------------- utility ----------------

__global__ void zero_kernel(float* __restrict__ p, int n4) {
    int i = blockIdx.x * blockDim.x + threadIdx.x;
    int stride = gridDim.x * blockDim.x;
    float4 z = make_float4(0.f, 0.f, 0.f, 0.f);
    for (; i < n4; i += stride) ((float4*)p)[i] = z;
}

__global__ void zero_int_kernel(int* __restrict__ p, int n) {
    int i = blockIdx.x * blockDim.x + threadIdx.x;
    int stride = gridDim.x * blockDim.x;
    for (; i < n; i += stride) p[i] = 0;
}

// fp32 -> fp16 table conversion (vectorized)
__global__ void f2h_kernel(const float4* __restrict__ in, __half2* __restrict__ out, int n4) {
    int i = blockIdx.x * blockDim.x + threadIdx.x;
    int stride = gridDim.x * blockDim.x;
    for (; i < n4; i += stride) {
        float4 v = in[i];
        out[2 * i + 0] = __floats2half2_rn(v.x, v.y);
        out[2 * i + 1] = __floats2half2_rn(v.z, v.w);
    }
}

// ---------------- CSR build ----------------

__global__ void count_kernel(const int* __restrict__ dst, int* __restrict__ cnt, int E) {
    int i = blockIdx.x * blockDim.x + threadIdx.x;
    int stride = gridDim.x * blockDim.x;
    for (; i < E; i += stride) atomicAdd(&cnt[dst[i]], 1);
}

__global__ void norm_from_cnt_kernel(const int* __restrict__ cnt, float* __restrict__ nrm, int n) {
    int i = blockIdx.x * blockDim.x + threadIdx.x;
    if (i < n) {
        float v = (float)cnt[i];
        v = v < 1.f ? 1.f : v;
        nrm[i] = 1.0f / sqrtf(v);
    }
}

// single-block exclusive scan via wave shuffles
__global__ __launch_bounds__(1024) void scan_kernel(const int* __restrict__ cnt,
                                                    int* __restrict__ rowptr, int n) {
    __shared__ int wsum[16];
    __shared__ int base;
    int t = threadIdx.x;
    int lane = t & 63, wv = t >> 6;
    if (t == 0) { base = 0; rowptr[0] = 0; }
    __syncthreads();
    for (int start = 0; start < n; start += 1024) {
        int i = start + t;
        int v = (i < n) ? cnt[i] : 0;
#pragma unroll
        for (int off = 1; off < 64; off <<= 1) {
            int u = __shfl_up(v, off);
            if (lane >= off) v += u;
        }
        if (lane == 63) wsum[wv] = v;
        __syncthreads();
        if (wv == 0) {
            int s = (lane < 16) ? wsum[lane] : 0;
#pragma unroll
            for (int off = 1; off < 16; off <<= 1) {
                int u = __shfl_up(s, off);
                if (lane >= off) s += u;
            }
            if (lane < 16) wsum[lane] = s;
        }
        __syncthreads();
        int woff = (wv > 0) ? wsum[wv - 1] : 0;
        if (i < n) rowptr[i + 1] = base + woff + v;
        __syncthreads();
        if (t == 0) base += wsum[15];
        __syncthreads();
    }
}

__global__ void copy_int_kernel(const int* __restrict__ a, int* __restrict__ b, int n) {
    int i = blockIdx.x * blockDim.x + threadIdx.x;
    int stride = gridDim.x * blockDim.x;
    for (; i < n; i += stride) b[i] = a[i];
}

__global__ void fill_kernel(const int* __restrict__ src, const int* __restrict__ dst,
                            int* __restrict__ rowcur, int* __restrict__ esrc, int E) {
    int i = blockIdx.x * blockDim.x + threadIdx.x;
    int stride = gridDim.x * blockDim.x;
    for (; i < E; i += stride) {
        int pos = atomicAdd(&rowcur[dst[i]], 1);
        esrc[pos] = src[i];
    }
}

// ---------------- propagation hop (fp16 gather, fp32 accumulate) ----------------
// out[i] = nrm[i] * sum_{e: dst=i} feat16[src]*nrm[src]
// One wave per node. QUARTER-wave per edge: row = 128 halfs = 256B = 16 lanes x
// half8 (uint4). 4 edges per wave-load; 2 bpermutes per 4 edges. Cross-quad
// combine via shfl_xor(16,32). Writes fp32 (GEMM operand) + optional fp16
// (next hop's gather table).

__global__ __launch_bounds__(256) void gather_hop_kernel(
    const __half* __restrict__ feat, const float* __restrict__ nrm,
    const int* __restrict__ rowptr, const int* __restrict__ esrc,
    float* __restrict__ outf, __half* __restrict__ outh, int n) {
    int wid = (blockIdx.x * blockDim.x + threadIdx.x) >> 6;
    int lane = threadIdx.x & 63;
    if (wid >= n) return;
    int beg = rowptr[wid], end = rowptr[wid + 1];
    int deg = end - beg;
    int quad = lane >> 4;   // which edge of the quad this quarter-wave handles
    int l16 = lane & 15;    // half8 slot within the 256B row
    float acc[8];
#pragma unroll
    for (int j = 0; j < 8; ++j) acc[j] = 0.f;
    for (int b = 0; b < deg; b += 64) {
        int rem = deg - b; if (rem > 64) rem = 64;
        int sE = 0; float wE = 0.f;  // lanes >= rem keep (0,0) -> phantom edges are no-ops
        if (lane < rem) {
            sE = esrc[beg + b + lane];
            wE = nrm[sE];
        }
        for (int k = 0; k < rem; k += 4) {
            int sel = k + quad;              // <= 63 always (k <= 60)
            int s = __shfl(sE, sel);
            float w = __shfl(wE, sel);       // phantom quads get w=0
            uint4 raw = *((const uint4*)(feat + (size_t)s * DIM) + l16);
            __half2 h0 = *(__half2*)&raw.x, h1 = *(__half2*)&raw.y;
            __half2 h2 = *(__half2*)&raw.z, h3 = *(__half2*)&raw.w;
            float2 f0 = __half22float2(h0), f1 = __half22float2(h1);
            float2 f2 = __half22float2(h2), f3 = __half22float2(h3);
            acc[0] += f0.x * w; acc[1] += f0.y * w;
            acc[2] += f1.x * w; acc[3] += f1.y * w;
            acc[4] += f2.x * w; acc[5] += f2.y * w;
            acc[6] += f3.x * w; acc[7] += f3.y * w;
        }
    }
    // combine the four quarter-wave partials (same dims, different edge subsets)
#pragma unroll
    for (int j = 0; j < 8; ++j) {
        acc[j] += __shfl_xor(acc[j], 16);
        acc[j] += __shfl_xor(acc[j], 32);
    }
    float nd = nrm[wid];
    if (lane < 16) {
        float4 o0 = make_float4(acc[0] * nd, acc[1] * nd, acc[2] * nd, acc[3] * nd);
        float4 o1 = make_float4(acc[4] * nd, acc[5] * nd, acc[6] * nd, acc[7] * nd);
        *(float4*)(outf + (size_t)wid * DIM + l16 * 8) = o0;
        *(float4*)(outf + (size_t)wid * DIM + l16 * 8 + 4) = o1;
        if (outh) {
            __half2 a0 = __floats2half2_rn(o0.x, o0.y), a1 = __floats2half2_rn(o0.z, o0.w);
            __half2 a2 = __floats2half2_rn(o1.x, o1.y), a3 = __floats2half2_rn(o1.z, o1.w);
            uint4 r;
            r.x = *(unsigned*)&a0; r.y = *(unsigned*)&a1;
            r.z = *(unsigned*)&a2; r.w = *(unsigned*)&a3;
            *(uint4*)(outh + (size_t)wid * DIM + l16 * 8) = r;
        }
    }
}

// ---------------- fp32 GEMM: out[M,128] = relu([A0|A1|A2] @ W + b) ----------------
// BM=64, 128 threads, per-thread 8x8 (rows {r0..+3, r0+32..+35}, cols
// {c0..+3, c0+64..+67}). LDS bytes/FMA = 1.0 (was 1.5 at 4x8) -> LDS-read
// floor ~47us vs measured 98us at R8. As reads are 4-address broadcasts;
// Wt reads 16 contiguous 16B lines (2-way = free). Register prefetch of next
// K-chunk. Grid 782 (~3 blocks/CU). In-place (out aliases A0) safe.
// Also emits fp16 copy of the output (next layer's gather table).

#define BM 64
#define BK 32

__global__ __launch_bounds__(128) void gemm_kernel(
    const float* __restrict__ A0, const float* __restrict__ A1, const float* __restrict__ A2,
    const float* __restrict__ W, const float* __restrict__ bias,
    float* __restrict__ out, __half* __restrict__ out16, int M) {
    __shared__ float As[BK][BM + 4];   // transposed A tile
    __shared__ float Wt[BK][DIM];

    int tid = threadIdx.x;
    int row0 = blockIdx.x * BM;
    int r0 = (tid >> 4) * 4;   // 8 row groups: {r0..r0+3} and {r0+32..r0+35}
    int c0 = (tid & 15) * 4;   // 16 col groups: {c0..c0+3} and {c0+64..c0+67}

    // staging coords
    int ar = tid >> 3;         // A row within tile (+16*it, it<4)
    int ak = (tid & 7) * 4;    // A k4
    int wk = tid >> 5;         // W k within chunk (+4*it, it<8)
    int wc = (tid & 31) * 4;   // W col

    const float* parts[3] = {A0, A1, A2};

    float4 pa[4], pw[8];
    // preload chunk 0 (p=0, kc=0)
#pragma unroll
    for (int it = 0; it < 4; ++it) {
        int grow = row0 + ar + 16 * it;
        pa[it] = (grow < M) ? *(const float4*)(A0 + (size_t)grow * DIM + ak)
                            : make_float4(0.f, 0.f, 0.f, 0.f);
    }
#pragma unroll
    for (int it = 0; it < 8; ++it) {
        pw[it] = *(const float4*)(W + (size_t)(wk + 4 * it) * DIM + wc);
    }

    float acc[8][8];
#pragma unroll
    for (int i = 0; i < 8; i++)
#pragma unroll
        for (int j = 0; j < 8; j++) acc[i][j] = 0.f;

    for (int t = 0; t < 12; ++t) {
        __syncthreads();
        // regs -> LDS
#pragma unroll
        for (int it = 0; it < 4; ++it) {
            int r = ar + 16 * it;
            As[ak + 0][r] = pa[it].x;
            As[ak + 1][r] = pa[it].y;
            As[ak + 2][r] = pa[it].z;
            As[ak + 3][r] = pa[it].w;
        }
#pragma unroll
        for (int it = 0; it < 8; ++it)
            *(float4*)(&Wt[wk + 4 * it][wc]) = pw[it];
        __syncthreads();
        // issue next chunk's loads; latency hides under the FMA block below
        if (t < 11) {
            int tn = t + 1;
            const float* A = parts[tn >> 2];
            int kc = (tn & 3) * BK;
#pragma unroll
            for (int it = 0; it < 4; ++it) {
                int grow = row0 + ar + 16 * it;
                pa[it] = (grow < M) ? *(const float4*)(A + (size_t)grow * DIM + kc + ak)
                                    : make_float4(0.f, 0.f, 0.f, 0.f);
            }
#pragma unroll
            for (int it = 0; it < 8; ++it)
                pw[it] = *(const float4*)(W + (size_t)((tn >> 2) * DIM + kc + wk + 4 * it) * DIM + wc);
        }
#pragma unroll
        for (int kk = 0; kk < BK; ++kk) {
            float4 a0 = *(const float4*)(&As[kk][r0]);
            float4 a1 = *(const float4*)(&As[kk][r0 + 32]);
            float4 w0 = *(const float4*)(&Wt[kk][c0]);
            float4 w1 = *(const float4*)(&Wt[kk][c0 + 64]);
            float a[8] = {a0.x, a0.y, a0.z, a0.w, a1.x, a1.y, a1.z, a1.w};
            float w[8] = {w0.x, w0.y, w0.z, w0.w, w1.x, w1.y, w1.z, w1.w};
#pragma unroll
            for (int i = 0; i < 8; i++)
#pragma unroll
                for (int j = 0; j < 8; j++) acc[i][j] += a[i] * w[j];
        }
    }

    // epilogue: bias + relu + float4 stores (+ fp16 copy)
#pragma unroll
    for (int i = 0; i < 8; i++) {
        int grow = row0 + (i < 4 ? r0 + i : 32 + r0 + i - 4);
        if (grow < M) {
            float4 o0, o1;
            o0.x = acc[i][0] + bias[c0 + 0]; o0.y = acc[i][1] + bias[c0 + 1];
            o0.z = acc[i][2] + bias[c0 + 2]; o0.w = acc[i][3] + bias[c0 + 3];
            o1.x = acc[i][4] + bias[c0 + 64 + 0]; o1.y = acc[i][5] + bias[c0 + 64 + 1];
            o1.z = acc[i][6] + bias[c0 + 64 + 2]; o1.w = acc[i][7] + bias[c0 + 64 + 3];
            o0.x = o0.x > 0.f ? o0.x : 0.f; o0.y = o0.y > 0.f ? o0.y : 0.f;
            o0.z = o0.z > 0.f ? o0.z : 0.f; o0.w = o0.w > 0.f ? o0.w : 0.f;
            o1.x = o1.x > 0.f ? o1.x : 0.f; o1.y = o1.y > 0.f ? o1.y : 0.f;
            o1.z = o1.z > 0.f ? o1.z : 0.f; o1.w = o1.w > 0.f ? o1.w : 0.f;
            *(float4*)(out + (size_t)grow * DIM + c0) = o0;
            *(float4*)(out + (size_t)grow * DIM + c0 + 64) = o1;
            if (out16) {
                __half2 p0 = __floats2half2_rn(o0.x, o0.y), p1 = __floats2half2_rn(o0.z, o0.w);
                __half2 q0 = __floats2half2_rn(o1.x, o1.y), q1 = __floats2half2_rn(o1.z, o1.w);
                uint2 ra, rb;
                ra.x = *(unsigned*)&p0; ra.y = *(unsigned*)&p1;
                rb.x = *(unsigned*)&q0; rb.y = *(unsigned*)&q1;
                *(uint2*)(out16 + (size_t)grow * DIM + c0) = ra;
                *(uint2*)(out16 + (size_t)grow * DIM + c0 + 64) = rb;
            }
        }
    }
}

// ---------------- pooling + head ----------------

#define PCHUNK 64

__global__ __launch_bounds__(128) void pool_partial_kernel(
    const float* __restrict__ h, const int* __restrict__ gid,
    float* __restrict__ gsum, int n) {
    int d = threadIdx.x;
    int i0 = blockIdx.x * PCHUNK;
    if (i0 >= n) return;
    int i1 = i0 + PCHUNK; if (i1 > n) i1 = n;
    int curg = gid[i0];
    float acc = 0.f;
    for (int i = i0; i < i1; ++i) {
        int g = gid[i];
        if (g != curg) {
            atomicAdd(&gsum[(size_t)curg * DIM + d], acc);
            acc = 0.f;
            curg = g;
        }
        acc += h[(size_t)i * DIM + d];
    }
    atomicAdd(&gsum[(size_t)curg * DIM + d], acc);
}

__global__ __launch_bounds__(128) void head_kernel(
    const float* __restrict__ gsum, const int* __restrict__ gid,
    const float* __restrict__ Wc, const float* __restrict__ bc,
    float* __restrict__ out) {
    __shared__ float v[DIM];
    __shared__ int sbeg, send;
    int g = blockIdx.x;
    int t = threadIdx.x;
    if (t == 0) {
        int lo = 0, hi = NN;
        while (lo < hi) { int m = (lo + hi) >> 1; if (gid[m] < g) lo = m + 1; else hi = m; }
        sbeg = lo;
    }
    if (t == 1) {
        int lo = 0, hi = NN;
        while (lo < hi) { int m = (lo + hi) >> 1; if (gid[m] < g + 1) lo = m + 1; else hi = m; }
        send = lo;
    }
    __syncthreads();
    float c = (float)(send - sbeg);
    c = c < 1.f ? 1.f : c;
    v[t] = gsum[(size_t)g * DIM + t] / c;
    __syncthreads();
    if (t < CLASSES) {
        float o = bc[t];
#pragma unroll 16
        for (int d = 0; d < DIM; ++d) o += v[d] * Wc[d * CLASSES + t];
        out[g * CLASSES + t] = o;
    }
}

// ---------------- launch ----------------

extern "C" void kernel_launch(void* const* d_in, const int* in_sizes, int n_in,
                              void* d_out, int out_size, void* d_ws, size_t ws_size,
                              hipStream_t stream) {
    const float* x   = (const float*)d_in[0];
    const int*   src = (const int*)d_in[1];
    const int*   dst = (const int*)d_in[2];
    const int*   gid = (const int*)d_in[3];
    const float* W0  = (const float*)d_in[4];
    const float* b0  = (const float*)d_in[5];
    const float* W1  = (const float*)d_in[6];
    const float* b1  = (const float*)d_in[7];
    const float* W2  = (const float*)d_in[8];
    const float* b2  = (const float*)d_in[9];
    const float* Wc  = (const float*)d_in[10];
    const float* bc  = (const float*)d_in[11];
    float* out = (float*)d_out;

    // workspace (float units): nrm[N] | h[N*D] | f1[N*D] | f2[N*D] | gsum[G*D]
    // then fp16 tables: x16[N*D] | h16[N*D] | a16[N*D]   (each N*D/2 float units)
    // then ints: cnt[N] | rowptr[N+1] | esrc[E]
    float* nrm  = (float*)d_ws;
    float* h    = nrm + NN;
    float* f1   = h + (size_t)NN * DIM;
    float* f2   = f1 + (size_t)NN * DIM;
    float* gsum = f2 + (size_t)NN * DIM;
    __half* x16 = (__half*)(gsum + (size_t)NG * DIM);
    __half* h16 = x16 + (size_t)NN * DIM;
    __half* a16 = h16 + (size_t)NN * DIM;
    int* cnt    = (int*)(a16 + (size_t)NN * DIM);
    int* rowptr = cnt + NN;
    int* esrc   = rowptr + NN + 1;

    // fp16 copy of x + CSR build (amortized over 6 hops)
    f2h_kernel<<<2048, 256, 0, stream>>>((const float4*)x, (__half2*)x16, NN * DIM / 4);
    zero_int_kernel<<<64, 256, 0, stream>>>(cnt, NN);
    count_kernel<<<1024, 256, 0, stream>>>(dst, cnt, NE);
    norm_from_cnt_kernel<<<(NN + 255) / 256, 256, 0, stream>>>(cnt, nrm, NN);
    scan_kernel<<<1, 1024, 0, stream>>>(cnt, rowptr, NN);
    copy_int_kernel<<<64, 256, 0, stream>>>(rowptr, cnt, NN);  // cnt becomes rowcur
    fill_kernel<<<1024, 256, 0, stream>>>(src, dst, cnt, esrc, NE);

    const float* Ws_[3] = {W0, W1, W2};
    const float* bs_[3] = {b0, b1, b2};
    const float* featIn = x;
    const __half* gin = x16;
    const int hop_blocks = (NN * 64 + 255) / 256;
    for (int l = 0; l < 3; ++l) {
        // hop1: gather gin -> f1 (fp32) + a16 (fp16, hop2's table)
        gather_hop_kernel<<<hop_blocks, 256, 0, stream>>>(gin, nrm, rowptr, esrc, f1, a16, NN);
        // hop2: gather a16 -> f2 (fp32); fp16 out not needed
        gather_hop_kernel<<<hop_blocks, 256, 0, stream>>>(a16, nrm, rowptr, esrc, f2, (__half*)0, NN);
        // gemm: [featIn|f1|f2]@W -> h (fp32) + h16 (next layer's gather table)
        gemm_kernel<<<(NN + BM - 1) / BM, 128, 0, stream>>>(
            featIn, f1, f2, Ws_[l], bs_[l], h, (l < 2) ? h16 : (__half*)0, NN);
        featIn = h;
        gin = h16;
    }

    // pooling + head
    zero_kernel<<<16, 256, 0, stream>>>(gsum, NG * DIM / 4);
    pool_partial_kernel<<<(NN + PCHUNK - 1) / PCHUNK, 128, 0, stream>>>(h, gid, gsum, NN);
    head_kernel<<<NG, DIM, 0, stream>>>(gsum, gid, Wc, bc, out);
}

// Round 14
// 621.975 us; speedup vs baseline: 1.4410x; 1.3562x over previous
//
#include <hip/hip_runtime.h>
#include <hip/hip_fp16.h>
#include <math.h>

#define NN 50000
#define NE 800000
#define NG 128
#define DIM 128
#define CLASSES 10

typedef _Float16 half8 __attribute__((ext_vector_type(8)));
typedef float f32x4 __attribute__((ext_vector_type(4)));

// ---------------- utility ----------------

__global__ void zero_kernel(float* __restrict__ p, int n4) {
    int i = blockIdx.x * blockDim.x + threadIdx.x;
    int stride = gridDim.x * blockDim.x;
    float4 z = make_float4(0.f, 0.f, 0.f, 0.f);
    for (; i < n4; i += stride) ((float4*)p)[i] = z;
}

__global__ void zero_int_kernel(int* __restrict__ p, int n) {
    int i = blockIdx.x * blockDim.x + threadIdx.x;
    int stride = gridDim.x * blockDim.x;
    for (; i < n; i += stride) p[i] = 0;
}

// fp32 -> fp16 table conversion (vectorized)
__global__ void f2h_kernel(const float4* __restrict__ in, __half2* __restrict__ out, int n4) {
    int i = blockIdx.x * blockDim.x + threadIdx.x;
    int stride = gridDim.x * blockDim.x;
    for (; i < n4; i += stride) {
        float4 v = in[i];
        out[2 * i + 0] = __floats2half2_rn(v.x, v.y);
        out[2 * i + 1] = __floats2half2_rn(v.z, v.w);
    }
}

// W [K=384][N=128] fp32 -> Wt [N=128][K=384] fp16 (transposed for contiguous
// per-lane B-fragment loads). 49152 elems, one-shot.
__global__ void wt16_kernel(const float* __restrict__ W, __half* __restrict__ Wt) {
    int i = blockIdx.x * blockDim.x + threadIdx.x;
    if (i < 384 * 128) {
        int k = i / 128, n = i % 128;     // consecutive threads: same k, consecutive n -> coalesced read
        Wt[(size_t)n * 384 + k] = __float2half(W[i]);
    }
}

// ---------------- CSR build ----------------

__global__ void count_kernel(const int* __restrict__ dst, int* __restrict__ cnt, int E) {
    int i = blockIdx.x * blockDim.x + threadIdx.x;
    int stride = gridDim.x * blockDim.x;
    for (; i < E; i += stride) atomicAdd(&cnt[dst[i]], 1);
}

__global__ void norm_from_cnt_kernel(const int* __restrict__ cnt, float* __restrict__ nrm, int n) {
    int i = blockIdx.x * blockDim.x + threadIdx.x;
    if (i < n) {
        float v = (float)cnt[i];
        v = v < 1.f ? 1.f : v;
        nrm[i] = 1.0f / sqrtf(v);
    }
}

// single-block exclusive scan via wave shuffles
__global__ __launch_bounds__(1024) void scan_kernel(const int* __restrict__ cnt,
                                                    int* __restrict__ rowptr, int n) {
    __shared__ int wsum[16];
    __shared__ int base;
    int t = threadIdx.x;
    int lane = t & 63, wv = t >> 6;
    if (t == 0) { base = 0; rowptr[0] = 0; }
    __syncthreads();
    for (int start = 0; start < n; start += 1024) {
        int i = start + t;
        int v = (i < n) ? cnt[i] : 0;
#pragma unroll
        for (int off = 1; off < 64; off <<= 1) {
            int u = __shfl_up(v, off);
            if (lane >= off) v += u;
        }
        if (lane == 63) wsum[wv] = v;
        __syncthreads();
        if (wv == 0) {
            int s = (lane < 16) ? wsum[lane] : 0;
#pragma unroll
            for (int off = 1; off < 16; off <<= 1) {
                int u = __shfl_up(s, off);
                if (lane >= off) s += u;
            }
            if (lane < 16) wsum[lane] = s;
        }
        __syncthreads();
        int woff = (wv > 0) ? wsum[wv - 1] : 0;
        if (i < n) rowptr[i + 1] = base + woff + v;
        __syncthreads();
        if (t == 0) base += wsum[15];
        __syncthreads();
    }
}

__global__ void copy_int_kernel(const int* __restrict__ a, int* __restrict__ b, int n) {
    int i = blockIdx.x * blockDim.x + threadIdx.x;
    int stride = gridDim.x * blockDim.x;
    for (; i < n; i += stride) b[i] = a[i];
}

__global__ void fill_kernel(const int* __restrict__ src, const int* __restrict__ dst,
                            int* __restrict__ rowcur, int* __restrict__ esrc, int E) {
    int i = blockIdx.x * blockDim.x + threadIdx.x;
    int stride = gridDim.x * blockDim.x;
    for (; i < E; i += stride) {
        int pos = atomicAdd(&rowcur[dst[i]], 1);
        esrc[pos] = src[i];
    }
}

// ---------------- propagation hop (fp16 gather, fp32 accumulate, fp16 out) ----------------
// outh[i] = half( nrm[i] * sum_{e: dst=i} feat16[src]*nrm[src] )

__global__ __launch_bounds__(256) void gather_hop_kernel(
    const __half* __restrict__ feat, const float* __restrict__ nrm,
    const int* __restrict__ rowptr, const int* __restrict__ esrc,
    __half* __restrict__ outh, int n) {
    int wid = (blockIdx.x * blockDim.x + threadIdx.x) >> 6;
    int lane = threadIdx.x & 63;
    if (wid >= n) return;
    int beg = rowptr[wid], end = rowptr[wid + 1];
    int deg = end - beg;
    int quad = lane >> 4;   // which edge of the quad this quarter-wave handles
    int l16 = lane & 15;    // half8 slot within the 256B row
    float acc[8];
#pragma unroll
    for (int j = 0; j < 8; ++j) acc[j] = 0.f;
    for (int b = 0; b < deg; b += 64) {
        int rem = deg - b; if (rem > 64) rem = 64;
        int sE = 0; float wE = 0.f;  // lanes >= rem keep (0,0) -> phantom edges are no-ops
        if (lane < rem) {
            sE = esrc[beg + b + lane];
            wE = nrm[sE];
        }
        for (int k = 0; k < rem; k += 4) {
            int sel = k + quad;              // <= 63 always (k <= 60)
            int s = __shfl(sE, sel);
            float w = __shfl(wE, sel);       // phantom quads get w=0
            uint4 raw = *((const uint4*)(feat + (size_t)s * DIM) + l16);
            __half2 h0 = *(__half2*)&raw.x, h1 = *(__half2*)&raw.y;
            __half2 h2 = *(__half2*)&raw.z, h3 = *(__half2*)&raw.w;
            float2 f0 = __half22float2(h0), f1 = __half22float2(h1);
            float2 f2 = __half22float2(h2), f3 = __half22float2(h3);
            acc[0] += f0.x * w; acc[1] += f0.y * w;
            acc[2] += f1.x * w; acc[3] += f1.y * w;
            acc[4] += f2.x * w; acc[5] += f2.y * w;
            acc[6] += f3.x * w; acc[7] += f3.y * w;
        }
    }
#pragma unroll
    for (int j = 0; j < 8; ++j) {
        acc[j] += __shfl_xor(acc[j], 16);
        acc[j] += __shfl_xor(acc[j], 32);
    }
    float nd = nrm[wid];
    if (lane < 16) {
        __half2 a0 = __floats2half2_rn(acc[0] * nd, acc[1] * nd);
        __half2 a1 = __floats2half2_rn(acc[2] * nd, acc[3] * nd);
        __half2 a2 = __floats2half2_rn(acc[4] * nd, acc[5] * nd);
        __half2 a3 = __floats2half2_rn(acc[6] * nd, acc[7] * nd);
        uint4 r;
        r.x = *(unsigned*)&a0; r.y = *(unsigned*)&a1;
        r.z = *(unsigned*)&a2; r.w = *(unsigned*)&a3;
        *(uint4*)(outh + (size_t)wid * DIM + l16 * 8) = r;
    }
}

// ---------------- MFMA fp16 GEMM: out[M,128] = relu([A0|A1|A2]@W + b) ----------------
// No LDS, no barriers. 256 threads = 4 waves as 2(M)x2(N); each wave owns a
// 32x64 output tile = 2x4 grid of 16x16 mfma tiles, acc in 32 VGPRs.
// v_mfma_f32_16x16x32_f16: lane l holds A[row=l&15][k=(l>>4)*8+j] (16B contiguous
// load from row-major fp16 A) and B[k=(l>>4)*8+j][col=l&15] (16B contiguous load
// from TRANSPOSED Wt[col][k]). D: col=l&15, row=(l>>4)*4+reg (m89 mapping).
// W (96KB fp16) is L2-resident across the 782 blocks; A rows read exactly once.

#define GBM 64

__global__ __launch_bounds__(256) void gemm_mfma_kernel(
    const __half* __restrict__ A0, const __half* __restrict__ A1, const __half* __restrict__ A2,
    const __half* __restrict__ Wt,   // [128][384] fp16
    const float* __restrict__ bias,
    float* __restrict__ out32, __half* __restrict__ out16, int M) {
    int tid = threadIdx.x;
    int wave = tid >> 6;
    int lane = tid & 63;
    int wm = wave >> 1;            // row half of block tile
    int wn = wave & 1;             // col half
    int row0 = blockIdx.x * GBM + wm * 32;
    int col0 = wn * 64;
    int lr = lane & 15;            // row (A) / col (B,D) within 16
    int lk = lane >> 4;            // k-octet selector

    const __half* parts[3] = {A0, A1, A2};

    f32x4 acc[2][4];
#pragma unroll
    for (int rg = 0; rg < 2; ++rg)
#pragma unroll
        for (int cg = 0; cg < 4; ++cg) acc[rg][cg] = (f32x4)0.f;

    half8 zero8 = {};

#pragma unroll
    for (int p = 0; p < 3; ++p) {
        const __half* A = parts[p];
#pragma unroll
        for (int cc = 0; cc < 4; ++cc) {
            int kloc = cc * 32 + lk * 8;             // k within part (0..127)
            int kglob = p * 128 + kloc;              // k within 384 (Wt row)
            half8 af[2];
#pragma unroll
            for (int rg = 0; rg < 2; ++rg) {
                int r = row0 + rg * 16 + lr;
                af[rg] = (r < M) ? *(const half8*)(A + (size_t)r * DIM + kloc) : zero8;
            }
            half8 bf[4];
#pragma unroll
            for (int cg = 0; cg < 4; ++cg) {
                int c = col0 + cg * 16 + lr;
                bf[cg] = *(const half8*)(Wt + (size_t)c * 384 + kglob);
            }
#pragma unroll
            for (int rg = 0; rg < 2; ++rg)
#pragma unroll
                for (int cg = 0; cg < 4; ++cg)
                    acc[rg][cg] = __builtin_amdgcn_mfma_f32_16x16x32_f16(
                        af[rg], bf[cg], acc[rg][cg], 0, 0, 0);
        }
    }

    // epilogue: bias + relu; D row = lk*4 + r, col = lr (within each 16x16 tile)
#pragma unroll
    for (int cg = 0; cg < 4; ++cg) {
        int c = col0 + cg * 16 + lr;
        float b = bias[c];
#pragma unroll
        for (int rg = 0; rg < 2; ++rg) {
#pragma unroll
            for (int r = 0; r < 4; ++r) {
                int row = row0 + rg * 16 + lk * 4 + r;
                if (row < M) {
                    float v = acc[rg][cg][r] + b;
                    v = v > 0.f ? v : 0.f;
                    if (out32) out32[(size_t)row * DIM + c] = v;
                    if (out16) out16[(size_t)row * DIM + c] = __float2half(v);
                }
            }
        }
    }
}

// ---------------- pooling + head ----------------

#define PCHUNK 64

__global__ __launch_bounds__(128) void pool_partial_kernel(
    const float* __restrict__ h, const int* __restrict__ gid,
    float* __restrict__ gsum, int n) {
    int d = threadIdx.x;
    int i0 = blockIdx.x * PCHUNK;
    if (i0 >= n) return;
    int i1 = i0 + PCHUNK; if (i1 > n) i1 = n;
    int curg = gid[i0];
    float acc = 0.f;
    for (int i = i0; i < i1; ++i) {
        int g = gid[i];
        if (g != curg) {
            atomicAdd(&gsum[(size_t)curg * DIM + d], acc);
            acc = 0.f;
            curg = g;
        }
        acc += h[(size_t)i * DIM + d];
    }
    atomicAdd(&gsum[(size_t)curg * DIM + d], acc);
}

__global__ __launch_bounds__(128) void head_kernel(
    const float* __restrict__ gsum, const int* __restrict__ gid,
    const float* __restrict__ Wc, const float* __restrict__ bc,
    float* __restrict__ out) {
    __shared__ float v[DIM];
    __shared__ int sbeg, send;
    int g = blockIdx.x;
    int t = threadIdx.x;
    if (t == 0) {
        int lo = 0, hi = NN;
        while (lo < hi) { int m = (lo + hi) >> 1; if (gid[m] < g) lo = m + 1; else hi = m; }
        sbeg = lo;
    }
    if (t == 1) {
        int lo = 0, hi = NN;
        while (lo < hi) { int m = (lo + hi) >> 1; if (gid[m] < g + 1) lo = m + 1; else hi = m; }
        send = lo;
    }
    __syncthreads();
    float c = (float)(send - sbeg);
    c = c < 1.f ? 1.f : c;
    v[t] = gsum[(size_t)g * DIM + t] / c;
    __syncthreads();
    if (t < CLASSES) {
        float o = bc[t];
#pragma unroll 16
        for (int d = 0; d < DIM; ++d) o += v[d] * Wc[d * CLASSES + t];
        out[g * CLASSES + t] = o;
    }
}

// ---------------- launch ----------------

extern "C" void kernel_launch(void* const* d_in, const int* in_sizes, int n_in,
                              void* d_out, int out_size, void* d_ws, size_t ws_size,
                              hipStream_t stream) {
    const float* x   = (const float*)d_in[0];
    const int*   src = (const int*)d_in[1];
    const int*   dst = (const int*)d_in[2];
    const int*   gid = (const int*)d_in[3];
    const float* W0  = (const float*)d_in[4];
    const float* b0  = (const float*)d_in[5];
    const float* W1  = (const float*)d_in[6];
    const float* b1  = (const float*)d_in[7];
    const float* W2  = (const float*)d_in[8];
    const float* b2  = (const float*)d_in[9];
    const float* Wc  = (const float*)d_in[10];
    const float* bc  = (const float*)d_in[11];
    float* out = (float*)d_out;

    // workspace (float units): nrm[N] | h[N*D] | gsum[G*D]
    // halves: x16 | f1h | f2h | h16a | h16b (each N*D) | wt0|wt1|wt2 (each 384*128)
    // ints: cnt[N] | rowptr[N+1] | esrc[E]
    float* nrm  = (float*)d_ws;
    float* h    = nrm + NN;
    float* gsum = h + (size_t)NN * DIM;
    __half* x16  = (__half*)(gsum + (size_t)NG * DIM);
    __half* f1h  = x16 + (size_t)NN * DIM;
    __half* f2h  = f1h + (size_t)NN * DIM;
    __half* h16a = f2h + (size_t)NN * DIM;
    __half* h16b = h16a + (size_t)NN * DIM;
    __half* wt0  = h16b + (size_t)NN * DIM;
    __half* wt1  = wt0 + 384 * 128;
    __half* wt2  = wt1 + 384 * 128;
    int* cnt    = (int*)(wt2 + 384 * 128);
    int* rowptr = cnt + NN;
    int* esrc   = rowptr + NN + 1;

    // fp16 conversions + CSR build
    f2h_kernel<<<2048, 256, 0, stream>>>((const float4*)x, (__half2*)x16, NN * DIM / 4);
    wt16_kernel<<<192, 256, 0, stream>>>(W0, wt0);
    wt16_kernel<<<192, 256, 0, stream>>>(W1, wt1);
    wt16_kernel<<<192, 256, 0, stream>>>(W2, wt2);
    zero_int_kernel<<<64, 256, 0, stream>>>(cnt, NN);
    count_kernel<<<1024, 256, 0, stream>>>(dst, cnt, NE);
    norm_from_cnt_kernel<<<(NN + 255) / 256, 256, 0, stream>>>(cnt, nrm, NN);
    scan_kernel<<<1, 1024, 0, stream>>>(cnt, rowptr, NN);
    copy_int_kernel<<<64, 256, 0, stream>>>(rowptr, cnt, NN);  // cnt becomes rowcur
    fill_kernel<<<1024, 256, 0, stream>>>(src, dst, cnt, esrc, NE);

    const __half* wts[3] = {wt0, wt1, wt2};
    const float* bs_[3] = {b0, b1, b2};
    const __half* gin = x16;
    __half* hbufs[2] = {h16a, h16b};
    const int hop_blocks = (NN * 64 + 255) / 256;
    for (int l = 0; l < 3; ++l) {
        gather_hop_kernel<<<hop_blocks, 256, 0, stream>>>(gin, nrm, rowptr, esrc, f1h, NN);
        gather_hop_kernel<<<hop_blocks, 256, 0, stream>>>(f1h, nrm, rowptr, esrc, f2h, NN);
        __half* hnext = (l < 2) ? hbufs[l & 1] : (__half*)0;
        gemm_mfma_kernel<<<(NN + GBM - 1) / GBM, 256, 0, stream>>>(
            gin, f1h, f2h, wts[l], bs_[l], (l == 2) ? h : (float*)0, hnext, NN);
        gin = hnext;
    }

    // pooling + head
    zero_kernel<<<16, 256, 0, stream>>>(gsum, NG * DIM / 4);
    pool_partial_kernel<<<(NN + PCHUNK - 1) / PCHUNK, 128, 0, stream>>>(h, gid, gsum, NN);
    head_kernel<<<NG, DIM, 0, stream>>>(gsum, gid, Wc, bc, out);
}

// Round 17
// 594.947 us; speedup vs baseline: 1.5064x; 1.0454x over previous
//
#include <hip/hip_runtime.h>
#include <hip/hip_fp16.h>
#include <math.h>

#define NN 50000
#define NE 800000
#define NG 128
#define DIM 128
#define CLASSES 10

typedef _Float16 half8 __attribute__((ext_vector_type(8)));
typedef float f32x4 __attribute__((ext_vector_type(4)));

// ---------------- utility ----------------

__global__ void zero_kernel(float* __restrict__ p, int n4) {
    int i = blockIdx.x * blockDim.x + threadIdx.x;
    int stride = gridDim.x * blockDim.x;
    float4 z = make_float4(0.f, 0.f, 0.f, 0.f);
    for (; i < n4; i += stride) ((float4*)p)[i] = z;
}

__global__ void zero_int_kernel(int* __restrict__ p, int n) {
    int i = blockIdx.x * blockDim.x + threadIdx.x;
    int stride = gridDim.x * blockDim.x;
    for (; i < n; i += stride) p[i] = 0;
}

// fp32 -> fp16 table conversion (vectorized)
__global__ void f2h_kernel(const float4* __restrict__ in, __half2* __restrict__ out, int n4) {
    int i = blockIdx.x * blockDim.x + threadIdx.x;
    int stride = gridDim.x * blockDim.x;
    for (; i < n4; i += stride) {
        float4 v = in[i];
        out[2 * i + 0] = __floats2half2_rn(v.x, v.y);
        out[2 * i + 1] = __floats2half2_rn(v.z, v.w);
    }
}

// All three W [384][128] fp32 -> Wt [128][384] fp16 (transposed), one launch.
__global__ void wt16x3_kernel(const float* __restrict__ W0, const float* __restrict__ W1,
                              const float* __restrict__ W2, __half* __restrict__ Wt0,
                              __half* __restrict__ Wt1, __half* __restrict__ Wt2) {
    int i = blockIdx.x * blockDim.x + threadIdx.x;
    if (i < 384 * 128) {
        int k = i / 128, n = i % 128;
        size_t o = (size_t)n * 384 + k;
        Wt0[o] = __float2half(W0[i]);
        Wt1[o] = __float2half(W1[i]);
        Wt2[o] = __float2half(W2[i]);
    }
}

// ---------------- CSR build ----------------

__global__ void count_kernel(const int* __restrict__ dst, int* __restrict__ cnt, int E) {
    int i = blockIdx.x * blockDim.x + threadIdx.x;
    int stride = gridDim.x * blockDim.x;
    for (; i < E; i += stride) atomicAdd(&cnt[dst[i]], 1);
}

__global__ void norm_from_cnt_kernel(const int* __restrict__ cnt, float* __restrict__ nrm, int n) {
    int i = blockIdx.x * blockDim.x + threadIdx.x;
    if (i < n) {
        float v = (float)cnt[i];
        v = v < 1.f ? 1.f : v;
        nrm[i] = 1.0f / sqrtf(v);
    }
}

// single-block exclusive scan via wave shuffles
__global__ __launch_bounds__(1024) void scan_kernel(const int* __restrict__ cnt,
                                                    int* __restrict__ rowptr, int n) {
    __shared__ int wsum[16];
    __shared__ int base;
    int t = threadIdx.x;
    int lane = t & 63, wv = t >> 6;
    if (t == 0) { base = 0; rowptr[0] = 0; }
    __syncthreads();
    for (int start = 0; start < n; start += 1024) {
        int i = start + t;
        int v = (i < n) ? cnt[i] : 0;
#pragma unroll
        for (int off = 1; off < 64; off <<= 1) {
            int u = __shfl_up(v, off);
            if (lane >= off) v += u;
        }
        if (lane == 63) wsum[wv] = v;
        __syncthreads();
        if (wv == 0) {
            int s = (lane < 16) ? wsum[lane] : 0;
#pragma unroll
            for (int off = 1; off < 16; off <<= 1) {
                int u = __shfl_up(s, off);
                if (lane >= off) s += u;
            }
            if (lane < 16) wsum[lane] = s;
        }
        __syncthreads();
        int woff = (wv > 0) ? wsum[wv - 1] : 0;
        if (i < n) rowptr[i + 1] = base + woff + v;
        __syncthreads();
        if (t == 0) base += wsum[15];
        __syncthreads();
    }
}

__global__ void copy_int_kernel(const int* __restrict__ a, int* __restrict__ b, int n) {
    int i = blockIdx.x * blockDim.x + threadIdx.x;
    int stride = gridDim.x * blockDim.x;
    for (; i < n; i += stride) b[i] = a[i];
}

// scatter edges: esrc is USHORT (src < 50000 < 65536) -> halves the
// write-amplified line traffic (R14: 53 MB WRITE_SIZE for 3.2 MB useful)
__global__ void fill_kernel(const int* __restrict__ src, const int* __restrict__ dst,
                            int* __restrict__ rowcur, unsigned short* __restrict__ esrc, int E) {
    int i = blockIdx.x * blockDim.x + threadIdx.x;
    int stride = gridDim.x * blockDim.x;
    for (; i < E; i += stride) {
        int pos = atomicAdd(&rowcur[dst[i]], 1);
        esrc[pos] = (unsigned short)src[i];
    }
}

// ---------------- propagation hop (fp16 gather, fp32 accumulate, fp16 out) ----------------
// outh[i] = half( nrm[i] * sum_{e: dst=i} feat16[src]*nrm[src] )
// One wave per node. QUARTER-wave per edge: row = 128 halfs = 256B = 16 lanes x
// half8 (uint4). Cross-quad combine via shfl_xor(16,32).

__global__ __launch_bounds__(256) void gather_hop_kernel(
    const __half* __restrict__ feat, const float* __restrict__ nrm,
    const int* __restrict__ rowptr, const unsigned short* __restrict__ esrc,
    __half* __restrict__ outh, int n) {
    int wid = (blockIdx.x * blockDim.x + threadIdx.x) >> 6;
    int lane = threadIdx.x & 63;
    if (wid >= n) return;
    int beg = rowptr[wid], end = rowptr[wid + 1];
    int deg = end - beg;
    int quad = lane >> 4;   // which edge of the quad this quarter-wave handles
    int l16 = lane & 15;    // half8 slot within the 256B row
    float acc[8];
#pragma unroll
    for (int j = 0; j < 8; ++j) acc[j] = 0.f;
    for (int b = 0; b < deg; b += 64) {
        int rem = deg - b; if (rem > 64) rem = 64;
        int sE = 0; float wE = 0.f;  // lanes >= rem keep (0,0) -> phantom edges are no-ops
        if (lane < rem) {
            sE = (int)esrc[beg + b + lane];
            wE = nrm[sE];
        }
        for (int k = 0; k < rem; k += 4) {
            int sel = k + quad;              // <= 63 always (k <= 60)
            int s = __shfl(sE, sel);
            float w = __shfl(wE, sel);       // phantom quads get w=0
            uint4 raw = *((const uint4*)(feat + (size_t)s * DIM) + l16);
            __half2 h0 = *(__half2*)&raw.x, h1 = *(__half2*)&raw.y;
            __half2 h2 = *(__half2*)&raw.z, h3 = *(__half2*)&raw.w;
            float2 f0 = __half22float2(h0), f1 = __half22float2(h1);
            float2 f2 = __half22float2(h2), f3 = __half22float2(h3);
            acc[0] += f0.x * w; acc[1] += f0.y * w;
            acc[2] += f1.x * w; acc[3] += f1.y * w;
            acc[4] += f2.x * w; acc[5] += f2.y * w;
            acc[6] += f3.x * w; acc[7] += f3.y * w;
        }
    }
#pragma unroll
    for (int j = 0; j < 8; ++j) {
        acc[j] += __shfl_xor(acc[j], 16);
        acc[j] += __shfl_xor(acc[j], 32);
    }
    float nd = nrm[wid];
    if (lane < 16) {
        __half2 a0 = __floats2half2_rn(acc[0] * nd, acc[1] * nd);
        __half2 a1 = __floats2half2_rn(acc[2] * nd, acc[3] * nd);
        __half2 a2 = __floats2half2_rn(acc[4] * nd, acc[5] * nd);
        __half2 a3 = __floats2half2_rn(acc[6] * nd, acc[7] * nd);
        uint4 r;
        r.x = *(unsigned*)&a0; r.y = *(unsigned*)&a1;
        r.z = *(unsigned*)&a2; r.w = *(unsigned*)&a3;
        *(uint4*)(outh + (size_t)wid * DIM + l16 * 8) = r;
    }
}

// ---------------- MFMA fp16 GEMM: out[M,128] = relu([A0|A1|A2]@W + b) ----------------
// No LDS, no barriers. 256 threads = 4 waves as 2(M)x2(N); each wave owns a
// 32x64 output tile = 2x4 grid of 16x16 mfma tiles, acc in 32 VGPRs.
// W (96KB fp16, transposed) is L2-resident across 782 blocks; A rows read once.

#define GBM 64

__global__ __launch_bounds__(256) void gemm_mfma_kernel(
    const __half* __restrict__ A0, const __half* __restrict__ A1, const __half* __restrict__ A2,
    const __half* __restrict__ Wt,   // [128][384] fp16
    const float* __restrict__ bias,
    float* __restrict__ out32, __half* __restrict__ out16, int M) {
    int tid = threadIdx.x;
    int wave = tid >> 6;
    int lane = tid & 63;
    int wm = wave >> 1;            // row half of block tile
    int wn = wave & 1;             // col half
    int row0 = blockIdx.x * GBM + wm * 32;
    int col0 = wn * 64;
    int lr = lane & 15;            // row (A) / col (B,D) within 16
    int lk = lane >> 4;            // k-octet selector

    const __half* parts[3] = {A0, A1, A2};

    f32x4 acc[2][4];
#pragma unroll
    for (int rg = 0; rg < 2; ++rg)
#pragma unroll
        for (int cg = 0; cg < 4; ++cg) acc[rg][cg] = (f32x4)0.f;

    half8 zero8 = {};

#pragma unroll
    for (int p = 0; p < 3; ++p) {
        const __half* A = parts[p];
#pragma unroll
        for (int cc = 0; cc < 4; ++cc) {
            int kloc = cc * 32 + lk * 8;             // k within part (0..127)
            int kglob = p * 128 + kloc;              // k within 384 (Wt row)
            half8 af[2];
#pragma unroll
            for (int rg = 0; rg < 2; ++rg) {
                int r = row0 + rg * 16 + lr;
                af[rg] = (r < M) ? *(const half8*)(A + (size_t)r * DIM + kloc) : zero8;
            }
            half8 bf[4];
#pragma unroll
            for (int cg = 0; cg < 4; ++cg) {
                int c = col0 + cg * 16 + lr;
                bf[cg] = *(const half8*)(Wt + (size_t)c * 384 + kglob);
            }
#pragma unroll
            for (int rg = 0; rg < 2; ++rg)
#pragma unroll
                for (int cg = 0; cg < 4; ++cg)
                    acc[rg][cg] = __builtin_amdgcn_mfma_f32_16x16x32_f16(
                        af[rg], bf[cg], acc[rg][cg], 0, 0, 0);
        }
    }

    // epilogue: bias + relu; D row = lk*4 + r, col = lr (within each 16x16 tile)
#pragma unroll
    for (int cg = 0; cg < 4; ++cg) {
        int c = col0 + cg * 16 + lr;
        float b = bias[c];
#pragma unroll
        for (int rg = 0; rg < 2; ++rg) {
#pragma unroll
            for (int r = 0; r < 4; ++r) {
                int row = row0 + rg * 16 + lk * 4 + r;
                if (row < M) {
                    float v = acc[rg][cg][r] + b;
                    v = v > 0.f ? v : 0.f;
                    if (out32) out32[(size_t)row * DIM + c] = v;
                    if (out16) out16[(size_t)row * DIM + c] = __float2half(v);
                }
            }
        }
    }
}

// ---------------- pooling + head ----------------

#define PCHUNK 64

__global__ __launch_bounds__(128) void pool_partial_kernel(
    const float* __restrict__ h, const int* __restrict__ gid,
    float* __restrict__ gsum, int n) {
    int d = threadIdx.x;
    int i0 = blockIdx.x * PCHUNK;
    if (i0 >= n) return;
    int i1 = i0 + PCHUNK; if (i1 > n) i1 = n;
    int curg = gid[i0];
    float acc = 0.f;
    for (int i = i0; i < i1; ++i) {
        int g = gid[i];
        if (g != curg) {
            atomicAdd(&gsum[(size_t)curg * DIM + d], acc);
            acc = 0.f;
            curg = g;
        }
        acc += h[(size_t)i * DIM + d];
    }
    atomicAdd(&gsum[(size_t)curg * DIM + d], acc);
}

__global__ __launch_bounds__(128) void head_kernel(
    const float* __restrict__ gsum, const int* __restrict__ gid,
    const float* __restrict__ Wc, const float* __restrict__ bc,
    float* __restrict__ out) {
    __shared__ float v[DIM];
    __shared__ int sbeg, send;
    int g = blockIdx.x;
    int t = threadIdx.x;
    if (t == 0) {
        int lo = 0, hi = NN;
        while (lo < hi) { int m = (lo + hi) >> 1; if (gid[m] < g) lo = m + 1; else hi = m; }
        sbeg = lo;
    }
    if (t == 1) {
        int lo = 0, hi = NN;
        while (lo < hi) { int m = (lo + hi) >> 1; if (gid[m] < g + 1) lo = m + 1; else hi = m; }
        send = lo;
    }
    __syncthreads();
    float c = (float)(send - sbeg);
    c = c < 1.f ? 1.f : c;
    v[t] = gsum[(size_t)g * DIM + t] / c;
    __syncthreads();
    if (t < CLASSES) {
        float o = bc[t];
#pragma unroll 16
        for (int d = 0; d < DIM; ++d) o += v[d] * Wc[d * CLASSES + t];
        out[g * CLASSES + t] = o;
    }
}

// ---------------- launch ----------------

extern "C" void kernel_launch(void* const* d_in, const int* in_sizes, int n_in,
                              void* d_out, int out_size, void* d_ws, size_t ws_size,
                              hipStream_t stream) {
    const float* x   = (const float*)d_in[0];
    const int*   src = (const int*)d_in[1];
    const int*   dst = (const int*)d_in[2];
    const int*   gid = (const int*)d_in[3];
    const float* W0  = (const float*)d_in[4];
    const float* b0  = (const float*)d_in[5];
    const float* W1  = (const float*)d_in[6];
    const float* b1  = (const float*)d_in[7];
    const float* W2  = (const float*)d_in[8];
    const float* b2  = (const float*)d_in[9];
    const float* Wc  = (const float*)d_in[10];
    const float* bc  = (const float*)d_in[11];
    float* out = (float*)d_out;

    // workspace (float units): nrm[N] | h[N*D] | gsum[G*D]
    // halves: x16 | f1h | f2h | h16a | h16b (each N*D) | wt0|wt1|wt2 (each 384*128)
    // ints: cnt[N] | rowptr[N+1] | then ushort esrc[E]
    float* nrm  = (float*)d_ws;
    float* h    = nrm + NN;
    float* gsum = h + (size_t)NN * DIM;
    __half* x16  = (__half*)(gsum + (size_t)NG * DIM);
    __half* f1h  = x16 + (size_t)NN * DIM;
    __half* f2h  = f1h + (size_t)NN * DIM;
    __half* h16a = f2h + (size_t)NN * DIM;
    __half* h16b = h16a + (size_t)NN * DIM;
    __half* wt0  = h16b + (size_t)NN * DIM;
    __half* wt1  = wt0 + 384 * 128;
    __half* wt2  = wt1 + 384 * 128;
    int* cnt    = (int*)(wt2 + 384 * 128);
    int* rowptr = cnt + NN;
    unsigned short* esrc = (unsigned short*)(rowptr + NN + 1);

    // fp16 conversions + CSR build
    f2h_kernel<<<2048, 256, 0, stream>>>((const float4*)x, (__half2*)x16, NN * DIM / 4);
    wt16x3_kernel<<<192, 256, 0, stream>>>(W0, W1, W2, wt0, wt1, wt2);
    zero_int_kernel<<<64, 256, 0, stream>>>(cnt, NN);
    count_kernel<<<1024, 256, 0, stream>>>(dst, cnt, NE);
    norm_from_cnt_kernel<<<(NN + 255) / 256, 256, 0, stream>>>(cnt, nrm, NN);
    scan_kernel<<<1, 1024, 0, stream>>>(cnt, rowptr, NN);
    copy_int_kernel<<<64, 256, 0, stream>>>(rowptr, cnt, NN);  // cnt becomes rowcur
    fill_kernel<<<1024, 256, 0, stream>>>(src, dst, cnt, esrc, NE);

    const __half* wts[3] = {wt0, wt1, wt2};
    const float* bs_[3] = {b0, b1, b2};
    const __half* gin = x16;
    __half* hbufs[2] = {h16a, h16b};
    const int hop_blocks = (NN * 64 + 255) / 256;
    for (int l = 0; l < 3; ++l) {
        gather_hop_kernel<<<hop_blocks, 256, 0, stream>>>(gin, nrm, rowptr, esrc, f1h, NN);
        gather_hop_kernel<<<hop_blocks, 256, 0, stream>>>(f1h, nrm, rowptr, esrc, f2h, NN);
        __half* hnext = (l < 2) ? hbufs[l & 1] : (__half*)0;
        gemm_mfma_kernel<<<(NN + GBM - 1) / GBM, 256, 0, stream>>>(
            gin, f1h, f2h, wts[l], bs_[l], (l == 2) ? h : (float*)0, hnext, NN);
        gin = hnext;
    }

    // pooling + head
    zero_kernel<<<16, 256, 0, stream>>>(gsum, NG * DIM / 4);
    pool_partial_kernel<<<(NN + PCHUNK - 1) / PCHUNK, 128, 0, stream>>>(h, gid, gsum, NN);
    head_kernel<<<NG, DIM, 0, stream>>>(gsum, gid, Wc, bc, out);
}